// Round 3
// baseline (82.617 us; speedup 1.0000x reference)
//
#include <hip/hip_runtime.h>
#include <hip/hip_bf16.h>

// Sizes (fixed by the problem)
#define NS   4096      // samples
#define NV   256       // variables/channels
#define NHID 64        // hidden
#define K2F  2.8853900817779268f   // 2*log2(e)

typedef short s8v __attribute__((ext_vector_type(8)));
typedef float f4v __attribute__((ext_vector_type(4)));

typedef __attribute__((address_space(1))) const unsigned int GU;
typedef __attribute__((address_space(3))) unsigned int LU;

__device__ __forceinline__ void gload16(const void* gp, void* lp) {
    __builtin_amdgcn_global_load_lds((GU*)gp, (LU*)lp, 16, 0, 0);
}

__device__ __forceinline__ unsigned short f2bf(float x) {
    __hip_bfloat16 h = __float2bfloat16(x);
    return *reinterpret_cast<unsigned short*>(&h);
}

// ---- prep: W2t[col][k] = adj[k,c] * w_in[c, k-(k>c), h],  col = c*64+h ----
__global__ __launch_bounds__(256) void k_prep_w2t(const float* __restrict__ adj,
                                                  const float* __restrict__ w_in,
                                                  unsigned short* __restrict__ W2t) {
    __shared__ float t[64][65];
    int c  = blockIdx.x >> 2;
    int k0 = (blockIdx.x & 3) * 64;
    int tid = threadIdx.x;
#pragma unroll
    for (int i = 0; i < 16; ++i) {
        int lin = i * 256 + tid;
        int kr = lin >> 6, h = lin & 63;
        int k = k0 + kr;
        float v = 0.0f;
        if (k != c) {
            int m = k - (k > c ? 1 : 0);
            v = adj[k * NV + c] * w_in[((size_t)c * 255 + m) * 64 + h];
        }
        t[kr][h] = v;
    }
    __syncthreads();
#pragma unroll
    for (int i = 0; i < 16; ++i) {
        int lin = i * 256 + tid;
        int h = lin >> 6, kr = lin & 63;
        W2t[((size_t)(c * 64 + h)) * NV + k0 + kr] = f2bf(t[kr][h]);
    }
}

// ---- prep (fused): data->bf16, out0=adj copy, g2/BO, bi2 ----
__global__ __launch_bounds__(256) void k_prep_small(
        const float* __restrict__ data, unsigned short* __restrict__ dataB,
        const float* __restrict__ adj,  float* __restrict__ out0,
        const float* __restrict__ neurons, const float* __restrict__ w_out,
        const float* __restrict__ b_out, float* __restrict__ g2, float* __restrict__ BO,
        const float* __restrict__ b_in, float* __restrict__ bi2)
{
    const int b = blockIdx.x, tid = threadIdx.x;
    if (b < 1024) {                       // data f32 -> bf16 (262144 float4)
        int i = b * 256 + tid;
        float4 v = reinterpret_cast<const float4*>(data)[i];
        ushort4 o = make_ushort4(f2bf(v.x), f2bf(v.y), f2bf(v.z), f2bf(v.w));
        reinterpret_cast<ushort4*>(dataB)[i] = o;
    } else if (b < 1088) {                // out0 = adj (16384 float4)
        int i = (b - 1024) * 256 + tid;
        reinterpret_cast<float4*>(out0)[i] = reinterpret_cast<const float4*>(adj)[i];
    } else if (b < 1152) {                // g2[j] = 2*neurons[h,c]*w_out[j]; BO[c]=b_out[c]+sum_h g
        int j = (b - 1088) * 256 + tid;
        int c = j >> 6, h = j & 63;
        float gv = neurons[h * NV + c] * w_out[j];
        g2[j] = 2.0f * gv;
        float s = gv;
        s += __shfl_xor(s, 1);  s += __shfl_xor(s, 2);  s += __shfl_xor(s, 4);
        s += __shfl_xor(s, 8);  s += __shfl_xor(s, 16); s += __shfl_xor(s, 32);
        if ((tid & 63) == 0) BO[c] = b_out[c] + s;
    } else {                              // bi2 = K2 * b_in (4096 float4)
        int i = (b - 1152) * 256 + tid;
        float4 v = reinterpret_cast<const float4*>(b_in)[i];
        v.x *= K2F; v.y *= K2F; v.z *= K2F; v.w *= K2F;
        reinterpret_cast<float4*>(bi2)[i] = v;
    }
}

// ---- main: 128x128 tile GEMM (4096x256 @ 256x16384), BK=64 double-buffered
// 4 waves (2x2, each 64x64), catalog 2-phase: STAGE at top, vmcnt(0)+barrier
// at iter end. Fused epilogue: out = BO - sum_h g2*rcp(1+exp2(K2*pre+bi2)).
__global__ __launch_bounds__(256, 2) void k_gemm_fused(
        const unsigned short* __restrict__ dataB,   // [4096][256] bf16
        const unsigned short* __restrict__ W2t,     // [16384][256] bf16
        const float* __restrict__ g2,               // [16384] 2*g
        const float* __restrict__ bi2,              // [16384] K2*b_in
        const float* __restrict__ BO,               // [256]  b_out + sum_h g
        float* __restrict__ out1)                   // [4096][256]
{
    __shared__ __align__(16) char lds[65536];       // buf0:[A 16K|B 16K] buf1:[A|B]
    const int tid  = threadIdx.x;
    const int w    = tid >> 6;
    const int lane = tid & 63;
    const int wr   = w >> 1, wc = w & 1;

    // XCD-chunked swizzle (4096 % 8 == 0 -> bijective): each XCD gets 16
    // n-tiles x all 32 m-tiles: B-strip 1MB + A 2MB = 3MB fits its 4MB L2.
    const int orig = (int)blockIdx.x;
    const int swz  = (orig & 7) * 512 + (orig >> 3);
    const int bm0  = (swz & 31) << 7;
    const int bn0  = (swz >> 5) << 7;

    // Epilogue operand prefetch (independent of the loop)
    const int cidx = (bn0 >> 6) + wc;               // this wave's channel c
    float g2r[4], bi2r[4];
#pragma unroll
    for (int ni = 0; ni < 4; ++ni) {
        int col = bn0 + wc * 64 + ni * 16 + (lane & 15);
        g2r[ni]  = g2[col];
        bi2r[ni] = bi2[col];
    }
    const float BOv = BO[cidx];

    f4v acc[4][4];
#pragma unroll
    for (int mi = 0; mi < 4; ++mi)
#pragma unroll
        for (int ni = 0; ni < 4; ++ni)
            acc[mi][ni] = (f4v){0.f, 0.f, 0.f, 0.f};

    // Staging offsets. LDS dest LINEAR (global_load_lds constraint); XOR
    // swizzle applied to the GLOBAL source + again on ds_read (rule #21).
    unsigned gA[4], gB[4], lo[4];
#pragma unroll
    for (int t = 0; t < 4; ++t) {
        int o     = w * 4096 + t * 1024 + lane * 16;  // byte offset in 16KB tile
        int row   = o >> 7;                           // 128B rows (64 bf16)
        int inner = (o & 127) ^ ((row & 7) << 4);     // inverse swizzle on source
        lo[t] = (unsigned)(w * 4096 + t * 1024);      // wave-uniform LDS base
        gA[t] = (unsigned)(bm0 + row) * 512u + (unsigned)inner;
        gB[t] = (unsigned)(bn0 + row) * 512u + (unsigned)inner;
    }
    const char* dA = (const char*)dataB;
    const char* dB = (const char*)W2t;

#define STAGE(KT, BUFO)                                                        \
    do {                                                                       \
        _Pragma("unroll")                                                      \
        for (int t = 0; t < 4; ++t)                                            \
            gload16(dA + (size_t)(gA[t] + (KT) * 128), lds + (BUFO) + lo[t]);  \
        _Pragma("unroll")                                                      \
        for (int t = 0; t < 4; ++t)                                            \
            gload16(dB + (size_t)(gB[t] + (KT) * 128), lds + (BUFO) + 16384 + lo[t]); \
    } while (0)

    // 2-deep prologue: tiles 0 and 1 in flight; wait only tile 0 (8 newer remain).
    STAGE(0, 0);
    STAGE(1, 32768);
    asm volatile("s_waitcnt vmcnt(8)" ::: "memory");
    __builtin_amdgcn_sched_barrier(0);
    __builtin_amdgcn_s_barrier();

#pragma unroll
    for (int kt = 0; kt < 4; ++kt) {
        const int bufo = (kt & 1) << 15;
        if (kt == 1) STAGE(2, 0);        // overwrites buf read at kt-1: safe, barrier passed
        if (kt == 2) STAGE(3, 32768);

#pragma unroll
        for (int kk = 0; kk < 2; ++kk) {
            s8v afr[4], bfr[4];
#pragma unroll
            for (int mi = 0; mi < 4; ++mi) {
                int ml    = wr * 64 + mi * 16 + (lane & 15);
                int inner = (kk * 64 + ((lane >> 4) << 4)) ^ ((ml & 7) << 4);
                afr[mi] = *reinterpret_cast<const s8v*>(lds + bufo + ml * 128 + inner);
            }
#pragma unroll
            for (int ni = 0; ni < 4; ++ni) {
                int nl    = wc * 64 + ni * 16 + (lane & 15);
                int inner = (kk * 64 + ((lane >> 4) << 4)) ^ ((nl & 7) << 4);
                bfr[ni] = *reinterpret_cast<const s8v*>(lds + bufo + 16384 + nl * 128 + inner);
            }
            __builtin_amdgcn_s_setprio(1);
#pragma unroll
            for (int mi = 0; mi < 4; ++mi)
#pragma unroll
                for (int ni = 0; ni < 4; ++ni)
                    acc[mi][ni] = __builtin_amdgcn_mfma_f32_16x16x32_bf16(
                        afr[mi], bfr[ni], acc[mi][ni], 0, 0, 0);
            __builtin_amdgcn_s_setprio(0);
        }

        if (kt < 3) {
            // drain the stage issued this iter (had a full compute phase to land)
            asm volatile("s_waitcnt vmcnt(0)" ::: "memory");
            __builtin_amdgcn_sched_barrier(0);
            __builtin_amdgcn_s_barrier();
        }
    }
#undef STAGE

    // Epilogue: out[n,c] = BO[c] - sum_h g2 * rcp(1 + exp2(K2*pre + bi2))
    // C/D layout: col = lane&15, row = (lane>>4)*4 + reg   [m89-verified]
#pragma unroll
    for (int mi = 0; mi < 4; ++mi) {
#pragma unroll
        for (int r = 0; r < 4; ++r) {
            float s = 0.f;
#pragma unroll
            for (int ni = 0; ni < 4; ++ni) {
                float m = __builtin_fmaf(acc[mi][ni][r], K2F, bi2r[ni]);
                float e = __builtin_amdgcn_exp2f(m);
                float rc = __builtin_amdgcn_rcpf(e + 1.0f);
                s = __builtin_fmaf(g2r[ni], rc, s);
            }
            s += __shfl_xor(s, 1);
            s += __shfl_xor(s, 2);
            s += __shfl_xor(s, 4);
            s += __shfl_xor(s, 8);
            if ((lane & 15) == 0) {
                int m = bm0 + wr * 64 + mi * 16 + ((lane >> 4) << 2) + r;
                out1[m * NV + cidx] = BOv - s;
            }
        }
    }
}

extern "C" void kernel_launch(void* const* d_in, const int* in_sizes, int n_in,
                              void* d_out, int out_size, void* d_ws, size_t ws_size,
                              hipStream_t stream) {
    const float* data    = (const float*)d_in[0];
    const float* adj     = (const float*)d_in[1];
    const float* neurons = (const float*)d_in[2];
    const float* w_in    = (const float*)d_in[3];
    const float* b_in    = (const float*)d_in[4];
    const float* w_out   = (const float*)d_in[5];
    const float* b_out   = (const float*)d_in[6];

    float* out0 = (float*)d_out;
    float* out1 = out0 + NV * NV;

    unsigned short* dataB = (unsigned short*)d_ws;                       // 2 MiB
    unsigned short* W2t   = (unsigned short*)((char*)d_ws + 2097152);    // 8 MiB
    float*          g2    = (float*)((char*)d_ws + 10485760);            // 64 KiB
    float*          bi2   = (float*)((char*)d_ws + 10551296);            // 64 KiB
    float*          BO    = (float*)((char*)d_ws + 10616832);            // 1 KiB

    hipLaunchKernelGGL(k_prep_w2t,   dim3(1024), dim3(256), 0, stream, adj, w_in, W2t);
    hipLaunchKernelGGL(k_prep_small, dim3(1168), dim3(256), 0, stream,
                       data, dataB, adj, out0, neurons, w_out, b_out, g2, BO, b_in, bi2);
    hipLaunchKernelGGL(k_gemm_fused, dim3(4096), dim3(256), 0, stream,
                       dataB, W2t, g2, bi2, BO, out1);
}